// Round 17
// baseline (128.462 us; speedup 1.0000x reference)
//
#include <hip/hip_runtime.h>

typedef __bf16 bf16x8 __attribute__((ext_vector_type(8)));
typedef float f32x4 __attribute__((ext_vector_type(4)));

static __device__ __forceinline__ unsigned short f2bf(float f) {
    union { float f; unsigned int u; } v; v.f = f;
    unsigned int r = v.u + 0x7fffu + ((v.u >> 16) & 1u);
    return (unsigned short)(r >> 16);
}
static __device__ __forceinline__ float blo(unsigned int u) {
    union { unsigned int u; float f; } v; v.u = u << 16; return v.f;
}
static __device__ __forceinline__ float bhi(unsigned int u) {
    union { unsigned int u; float f; } v; v.u = u & 0xffff0000u; return v.f;
}
static __device__ __forceinline__ unsigned int pack2(float a, float b) {
    return (unsigned int)f2bf(a) | ((unsigned int)f2bf(b) << 16);
}

// ---- fast zero ----
__global__ void zero_kernel(int* __restrict__ p, int n) {
    int i = blockIdx.x * blockDim.x + threadIdx.x;
    int n4 = n >> 2;
    if (i < n4) reinterpret_cast<int4*>(p)[i] = make_int4(0, 0, 0, 0);
    if (i < (n & 3)) p[(n4 << 2) + i] = 0;
}

// ---- fused prep: [0,nh) hist+eoff | [nh,nh+nx) x->bf16 slice | rest: Wt2 transpose ----
__global__ __launch_bounds__(256) void prep_kernel(
    const int* __restrict__ dst, const int* __restrict__ et,
    int* __restrict__ deg, int* __restrict__ eoff,
    const float* __restrict__ x, unsigned short* __restrict__ s,
    const float* __restrict__ Wr, const float* __restrict__ W0w,
    unsigned short* __restrict__ Wt2,
    int E, int N, int R, int nh, int nx)
{
    __shared__ float t[64][65];
    const int bid = blockIdx.x, tid = threadIdx.x;
    const int K = (R + 1) * 256;
    if (bid < nh) {
        int i = bid * 256 + tid;
        if (i < E) eoff[i] = atomicAdd(&deg[et[i] * N + dst[i]], 1);
    } else if (bid < nh + nx) {
        int id = (bid - nh) * 256 + tid;
        int n = id >> 6, c4 = id & 63;
        if (n < N) {
            float4 v = *reinterpret_cast<const float4*>(&x[((size_t)n << 8) + (c4 << 2)]);
            ushort4 h;
            h.x = f2bf(v.x); h.y = f2bf(v.y); h.z = f2bf(v.z); h.w = f2bf(v.w);
            *reinterpret_cast<ushort4*>(&s[(size_t)n * K + (K - 256) + (c4 << 2)]) = h;
        }
    } else {
        int tb = bid - nh - nx;              // (R+1)*16 tiles
        int sl = tb >> 4, d0 = ((tb >> 2) & 3) * 64, o0 = (tb & 3) * 64;
        if (sl < R) {
            #pragma unroll
            for (int j = 0; j < 16; ++j) {
                int idx = j * 256 + tid;
                int dr = idx >> 6, oc = idx & 63;
                t[dr][oc] = Wr[((size_t)sl * 256 + d0 + dr) * 256 + o0 + oc];
            }
            __syncthreads();
            #pragma unroll
            for (int j = 0; j < 4; ++j) {
                int idx = j * 256 + tid;
                int orow = idx >> 4, dc4 = (idx & 15) << 2;
                ushort4 h;
                h.x = f2bf(t[dc4 + 0][orow]); h.y = f2bf(t[dc4 + 1][orow]);
                h.z = f2bf(t[dc4 + 2][orow]); h.w = f2bf(t[dc4 + 3][orow]);
                *reinterpret_cast<ushort4*>(&Wt2[(size_t)(o0 + orow) * K + sl * 256 + d0 + dc4]) = h;
            }
        } else {
            #pragma unroll
            for (int j = 0; j < 4; ++j) {
                int idx = j * 256 + tid;
                int orow = idx >> 4, dc4 = (idx & 15) << 2;
                float4 v = *reinterpret_cast<const float4*>(&W0w[(size_t)(o0 + orow) * 256 + d0 + dc4]);
                ushort4 h;
                h.x = f2bf(v.x); h.y = f2bf(v.y); h.z = f2bf(v.z); h.w = f2bf(v.w);
                *reinterpret_cast<ushort4*>(&Wt2[(size_t)(o0 + orow) * K + sl * 256 + d0 + dc4]) = h;
            }
        }
    }
}

// ---- 2-level exclusive scan over B bins (chunk=256) ----
__global__ void scan1_kernel(const int* __restrict__ deg, int* __restrict__ local,
                             int* __restrict__ bsum, int B) {
    __shared__ int tmp[256];
    int t = threadIdx.x, g = blockIdx.x * 256 + t;
    int v = (g < B) ? deg[g] : 0;
    tmp[t] = v; __syncthreads();
    for (int o = 1; o < 256; o <<= 1) {
        int u = (t >= o) ? tmp[t - o] : 0;
        __syncthreads();
        tmp[t] += u;
        __syncthreads();
    }
    if (g < B) local[g] = tmp[t] - v;
    if (t == 255) bsum[blockIdx.x] = tmp[t];
}

__global__ void scan2_kernel(const int* __restrict__ bsum, int* __restrict__ base, int nc) {
    __shared__ int tmp[1024];
    int t = threadIdx.x;
    int v = (t < nc) ? bsum[t] : 0;
    tmp[t] = v; __syncthreads();
    for (int o = 1; o < 1024; o <<= 1) {
        int u = (t >= o) ? tmp[t - o] : 0;
        __syncthreads();
        tmp[t] += u;
        __syncthreads();
    }
    if (t < nc) base[t] = tmp[t] - v;
}

// ---- bucket edges (atomic-free): pos = local+base+eoff ----
__global__ void scatter_ids_kernel(const int* __restrict__ src, const int* __restrict__ dst,
                                   const int* __restrict__ et, const int* __restrict__ local,
                                   const int* __restrict__ base, const int* __restrict__ eoff,
                                   int* __restrict__ srcs, int E, int N) {
    int i = blockIdx.x * blockDim.x + threadIdx.x;
    if (i < E) {
        int b = et[i] * N + dst[i];
        srcs[local[b] + base[b >> 8] + eoff[i]] = src[i];
    }
}

// ---- segment reduce: half-wave (32 lanes x 16B) per (r,dn) bin; 2 bins/wave ----
__global__ __launch_bounds__(256) void reduce_kernel(
    const int* __restrict__ srcs, const int* __restrict__ deg,
    const int* __restrict__ local, const int* __restrict__ base,
    unsigned short* __restrict__ s, int N, int R)
{
    const int K = (R + 1) * 256;
    const int r = blockIdx.y;
    const int dn = blockIdx.x * 8 + (threadIdx.x >> 5);
    if (dn >= N) return;
    const int lane = threadIdx.x & 31;
    const int bin = r * N + dn;
    const int cnt = deg[bin];
    const int st  = local[bin] + base[bin >> 8];

    float a0 = 0.f, a1 = 0.f, a2 = 0.f, a3 = 0.f;
    float a4 = 0.f, a5 = 0.f, a6 = 0.f, a7 = 0.f;
    for (int c0 = 0; c0 < cnt; c0 += 32) {
        int sv = 0;
        if (c0 + lane < cnt) sv = srcs[st + c0 + lane];
        int m = cnt - c0; if (m > 32) m = 32;
        for (int i = 0; i < m; ++i) {
            int sn = __shfl(sv, i, 32);
            const uint4 v = *reinterpret_cast<const uint4*>(
                &s[(size_t)sn * K + (K - 256) + (lane << 3)]);
            a0 += blo(v.x); a1 += bhi(v.x);
            a2 += blo(v.y); a3 += bhi(v.y);
            a4 += blo(v.z); a5 += bhi(v.z);
            a6 += blo(v.w); a7 += bhi(v.w);
        }
    }
    if (cnt > 0) {
        float sc = 1.0f / (float)cnt;
        a0 *= sc; a1 *= sc; a2 *= sc; a3 *= sc;
        a4 *= sc; a5 *= sc; a6 *= sc; a7 *= sc;
    }
    uint4 o;
    o.x = pack2(a0, a1); o.y = pack2(a2, a3);
    o.z = pack2(a4, a5); o.w = pack2(a6, a7);
    *reinterpret_cast<uint4*>(&s[(size_t)dn * K + (r << 8) + (lane << 3)]) = o;
}

// ---- dense GEMM, full-N 64x256 tile, uneven split-K, bf16 LDS-repack epilogue ----
// C_partial[z][M,256](bf16) = A[M,Kz](s) * B[256,Kz](Wt2)^T
// Grid (nM64, KZ), nM64=ceil(M/64). Tile M=64, N=256 (full width) -> no A
// row-tile is read by two blocks (kills the duplicate A fetch R13's swizzle
// only mitigated). 4 waves 2x2: wave covers 32 rows x 128 cols, acc[2][8] ->
// 16 MFMA/wave/k-step (same barrier amortization as the verified 128x128;
// R6's failure halved this). BK=64; A dbuf (2 ahead, 2 issues/thread),
// B single-buffered (8 issues/thread); counted vmcnt(2); LDS 48KB -> 3 blocks/CU.
__global__ __launch_bounds__(256) void gemm_kernel(
    const unsigned short* __restrict__ S, const unsigned short* __restrict__ Wt2,
    unsigned short* __restrict__ pbuf, int M, int K, int ktot, int KZ)
{
    __shared__ __align__(16) unsigned short ldsA[2][4096];   // 2 x 64 rows x 64 k (16KB)
    __shared__ __align__(16) unsigned short ldsB[16384];     // 256 rows x 64 k (32KB)
    const int tid = threadIdx.x;
    const int lane = tid & 63, w = tid >> 6;
    const int wm = w & 1, wn = w >> 1;

    // XCD-chunked remap (kept from R13; harmless here, groups z-slices per XCD)
    const int nM = gridDim.x;
    const int nwg = nM * gridDim.y;
    int L = blockIdx.x + nM * blockIdx.y;
    if ((nwg & 7) == 0) { int q = nwg >> 3; L = (L & 7) * q + (L >> 3); }
    const int z = L / nM;
    const int m0 = (L - z * nM) * 64;
    const int kb_ = ktot / KZ;
    const int krem = ktot - kb_ * KZ;
    const int ksteps = kb_ + (z < krem ? 1 : 0);
    const int kstart = (z * kb_ + (z < krem ? z : krem)) * 64;
    const size_t rowb = (size_t)K * 2;

    f32x4 acc[2][8] = {};

#define STAGE_A(buf, kstep)                                                               \
    {                                                                                     \
        const int kb = (kstart + (kstep) * 64) * 2;                                       \
        _Pragma("unroll")                                                                 \
        for (int i = 0; i < 2; ++i) {                                                     \
            int flat = (w * 2 + i) * 64 + lane;                                           \
            int row = flat >> 3, seg = flat & 7;                                          \
            int gr = m0 + row; gr = gr < M ? gr : M - 1;                                  \
            const char* gp = (const char*)S + (size_t)gr * rowb + kb                      \
                             + ((seg * 16) ^ ((row & 7) << 4));                           \
            unsigned short* lp = &ldsA[buf][(w * 2 + i) * 512];                           \
            __builtin_amdgcn_global_load_lds(                                             \
                (const __attribute__((address_space(1))) void*)gp,                        \
                (__attribute__((address_space(3))) void*)lp, 16, 0, 0);                   \
        }                                                                                 \
    }

#define STAGE_B(kstep)                                                                    \
    {                                                                                     \
        const int kb = (kstart + (kstep) * 64) * 2;                                       \
        _Pragma("unroll")                                                                 \
        for (int i = 0; i < 8; ++i) {                                                     \
            int flat = (w * 8 + i) * 64 + lane;                                           \
            int row = flat >> 3, seg = flat & 7;                                          \
            const char* gp = (const char*)Wt2 + (size_t)row * rowb + kb                   \
                             + ((seg * 16) ^ ((row & 7) << 4));                           \
            unsigned short* lp = &ldsB[(w * 8 + i) * 512];                                \
            __builtin_amdgcn_global_load_lds(                                             \
                (const __attribute__((address_space(1))) void*)gp,                        \
                (__attribute__((address_space(3))) void*)lp, 16, 0, 0);                   \
        }                                                                                 \
    }

#define COMPUTE(buf)                                                                      \
    {                                                                                     \
        _Pragma("unroll")                                                                 \
        for (int kk = 0; kk < 2; ++kk) {                                                  \
            bf16x8 af[2], bfr[8];                                                         \
            _Pragma("unroll")                                                             \
            for (int m = 0; m < 2; ++m) {                                                 \
                int row = wm * 32 + m * 16 + (lane & 15);                                 \
                int colb = (kk * 64 + ((lane >> 4) << 4)) ^ ((row & 7) << 4);             \
                af[m] = *reinterpret_cast<const bf16x8*>(                                 \
                    (const char*)&ldsA[buf][0] + row * 128 + colb);                       \
            }                                                                             \
            _Pragma("unroll")                                                             \
            for (int n = 0; n < 8; ++n) {                                                 \
                int row = wn * 128 + n * 16 + (lane & 15);                                \
                int colb = (kk * 64 + ((lane >> 4) << 4)) ^ ((row & 7) << 4);             \
                bfr[n] = *reinterpret_cast<const bf16x8*>(                                \
                    (const char*)&ldsB[0] + row * 128 + colb);                            \
            }                                                                             \
            __builtin_amdgcn_s_setprio(1);                                                \
            _Pragma("unroll")                                                             \
            for (int m = 0; m < 2; ++m)                                                   \
                _Pragma("unroll")                                                         \
                for (int n = 0; n < 8; ++n)                                               \
                    acc[m][n] = __builtin_amdgcn_mfma_f32_16x16x32_bf16(                  \
                        af[m], bfr[n], acc[m][n], 0, 0, 0);                               \
            __builtin_amdgcn_s_setprio(0);                                                \
        }                                                                                 \
    }

    STAGE_A(0, 0)
    STAGE_B(0)
    STAGE_A(1, 1)
    asm volatile("s_waitcnt vmcnt(2)" ::: "memory");
    __builtin_amdgcn_s_barrier();

    for (int t = 0; t < ksteps; ++t) {
        COMPUTE(t & 1)
        asm volatile("s_waitcnt lgkmcnt(0)" ::: "memory");
        __builtin_amdgcn_sched_barrier(0);
        __builtin_amdgcn_s_barrier();
        if (t + 1 < ksteps) {
            STAGE_B(t + 1)
            if (t + 2 < ksteps) {
                STAGE_A(t & 1, t + 2)
                asm volatile("s_waitcnt vmcnt(2)" ::: "memory");
            } else {
                asm volatile("s_waitcnt vmcnt(0)" ::: "memory");
            }
            __builtin_amdgcn_s_barrier();
        }
    }
#undef STAGE_A
#undef STAGE_B
#undef COMPUTE

    // ---- epilogue: repack acc -> ldsB as 64x256 bf16 tile -> coalesced stores ----
    // (barrier after final COMPUTE guarantees all waves done reading ldsB)
    unsigned short* ldsC = &ldsB[0];
    const int lr = wm * 32 + ((lane >> 4) << 2);
    const int lc = wn * 128 + (lane & 15);
    #pragma unroll
    for (int n = 0; n < 8; ++n)
        #pragma unroll
        for (int m = 0; m < 2; ++m)
            #pragma unroll
            for (int j = 0; j < 4; ++j)
                ldsC[(lr + m * 16 + j) * 256 + lc + n * 16] = f2bf(acc[m][n][j]);
    __syncthreads();
    unsigned short* dstp = pbuf + (size_t)z * M * 256;
    #pragma unroll
    for (int i = 0; i < 8; ++i) {
        int idx = tid + i * 256;          // 0..2047
        int row = idx >> 5, ch = idx & 31;
        int gr = m0 + row;
        if (gr < M)
            *reinterpret_cast<uint4*>(&dstp[(size_t)gr * 256 + ch * 8]) =
                *reinterpret_cast<const uint4*>(&ldsC[row * 256 + ch * 8]);
    }
}

// ---- combine bf16 split-K partials + bias -> f32 out ----
__global__ void combine_kernel(const unsigned short* __restrict__ pbuf,
                               const float* __restrict__ bias,
                               float* __restrict__ out, int M, int KZ) {
    int id = blockIdx.x * blockDim.x + threadIdx.x;
    if (id >= M * 64) return;
    int n = id >> 6, c4 = id & 63;
    const float4 bv = *reinterpret_cast<const float4*>(&bias[c4 << 2]);
    float4 a = bv;
    for (int kz = 0; kz < KZ; ++kz) {
        uint2 v = *reinterpret_cast<const uint2*>(
            &pbuf[(size_t)kz * M * 256 + ((size_t)n << 8) + (c4 << 2)]);
        a.x += blo(v.x); a.y += bhi(v.x);
        a.z += blo(v.y); a.w += bhi(v.y);
    }
    *reinterpret_cast<float4*>(&out[((size_t)n << 8) + (c4 << 2)]) = a;
}

extern "C" void kernel_launch(void* const* d_in, const int* in_sizes, int n_in,
                              void* d_out, int out_size, void* d_ws, size_t ws_size,
                              hipStream_t stream) {
    const float* x   = (const float*)d_in[0];
    const float* Wr  = (const float*)d_in[1];
    const float* W0w = (const float*)d_in[2];
    const float* W0b = (const float*)d_in[3];
    const int*   eidx= (const int*)d_in[4];
    const int*   et  = (const int*)d_in[5];
    const int N = in_sizes[0] / 256;      // nodes (10000)
    const int R = in_sizes[1] / 65536;    // relations (16)
    const int E = in_sizes[5];            // edges (320000)
    const int* src = eidx;
    const int* dst = eidx + E;
    float* out = (float*)d_out;

    const int B = R * N;                  // bins
    const int NC = (B + 255) / 256;       // scan chunks (<=1024)
    const int K = (R + 1) * 256;          // 4352

    // ---- workspace layout: [region0 = max(pbuf bf16, sortbufs)] [Wt2] [s] ----
    const size_t sz_pslice = (size_t)N * 256 * 2;                 // bf16 partial slice
    const size_t sz_sort = (((size_t)B * 4 + 255) & ~255UL) * 2   // deg, local
                         + (((size_t)E * 4 + 255) & ~255UL) * 2   // eoff, srcs
                         + 2 * 4096;                              // bsum, base
    const size_t sz_wt2 = (size_t)256 * K * 2;
    const size_t sz_s   = (size_t)N * K * 2;
    int KZ = 1;
    for (int kz = 8; kz >= 1; kz >>= 1) {
        size_t r0 = (kz > 1) ? (size_t)kz * sz_pslice : sz_pslice;
        if (sz_sort > r0) r0 = sz_sort;
        size_t need = ((r0 + 255) & ~255UL) + ((sz_wt2 + 255) & ~255UL) + sz_s + 1024;
        if (need <= ws_size || kz == 1) { KZ = kz; break; }
    }

    char* ws = (char*)d_ws;
    size_t off = 0;
    auto alloc = [&](size_t bytes) { void* p = ws + off; off = (off + bytes + 255) & ~(size_t)255; return p; };
    unsigned short* pbuf = (unsigned short*)ws;  // aliases sort bufs (dead before gemm)
    int* deg    = (int*)alloc((size_t)B * 4);
    int* local  = (int*)alloc((size_t)B * 4);
    int* bsum   = (int*)alloc(4096);
    int* base   = (int*)alloc(4096);
    int* eoff   = (int*)alloc((size_t)E * 4);
    int* srcs   = (int*)alloc((size_t)E * 4);
    size_t region0 = (size_t)KZ * sz_pslice;
    if (off > region0) region0 = off;
    off = (region0 + 255) & ~(size_t)255;
    unsigned short* Wt2 = (unsigned short*)alloc(sz_wt2);
    unsigned short* s   = (unsigned short*)alloc(sz_s);

    zero_kernel<<<(B / 4 + 255) / 256, 256, 0, stream>>>(deg, B);
    {
        const int nh = (E + 255) / 256;
        const int nx = (N * 64 + 255) / 256;
        const int nwT = (R + 1) * 16;
        prep_kernel<<<nh + nx + nwT, 256, 0, stream>>>(dst, et, deg, eoff, x, s,
                                                       Wr, W0w, Wt2, E, N, R, nh, nx);
    }
    scan1_kernel<<<NC, 256, 0, stream>>>(deg, local, bsum, B);
    scan2_kernel<<<1, 1024, 0, stream>>>(bsum, base, NC);
    scatter_ids_kernel<<<(E + 255) / 256, 256, 0, stream>>>(src, dst, et, local, base, eoff, srcs, E, N);
    {
        dim3 g((N + 7) / 8, R);
        reduce_kernel<<<g, 256, 0, stream>>>(srcs, deg, local, base, s, N, R);
    }
    {
        const int ktot = K / 64;                  // 68
        const int nM64 = (N + 63) / 64;           // 157
        dim3 grid(nM64, KZ);                      // bx=m-tile, by=kz
        gemm_kernel<<<grid, 256, 0, stream>>>(s, Wt2, pbuf, N, K, ktot, KZ);
        combine_kernel<<<(N * 64 + 255) / 256, 256, 0, stream>>>(pbuf, W0b, out, N, KZ);
    }
}

// Round 18
// 118.386 us; speedup vs baseline: 1.0851x; 1.0851x over previous
//
#include <hip/hip_runtime.h>

typedef __bf16 bf16x8 __attribute__((ext_vector_type(8)));
typedef float f32x4 __attribute__((ext_vector_type(4)));

static __device__ __forceinline__ unsigned short f2bf(float f) {
    union { float f; unsigned int u; } v; v.f = f;
    unsigned int r = v.u + 0x7fffu + ((v.u >> 16) & 1u);
    return (unsigned short)(r >> 16);
}
static __device__ __forceinline__ float blo(unsigned int u) {
    union { unsigned int u; float f; } v; v.u = u << 16; return v.f;
}
static __device__ __forceinline__ float bhi(unsigned int u) {
    union { unsigned int u; float f; } v; v.u = u & 0xffff0000u; return v.f;
}
static __device__ __forceinline__ unsigned int pack2(float a, float b) {
    return (unsigned int)f2bf(a) | ((unsigned int)f2bf(b) << 16);
}

// ---- fast zero ----
__global__ void zero_kernel(int* __restrict__ p, int n) {
    int i = blockIdx.x * blockDim.x + threadIdx.x;
    int n4 = n >> 2;
    if (i < n4) reinterpret_cast<int4*>(p)[i] = make_int4(0, 0, 0, 0);
    if (i < (n & 3)) p[(n4 << 2) + i] = 0;
}

// ---- fused prep: [0,nh) hist+eoff | [nh,nh+nx) x->bf16 slice | rest: Wt2 transpose ----
__global__ __launch_bounds__(256) void prep_kernel(
    const int* __restrict__ dst, const int* __restrict__ et,
    int* __restrict__ deg, int* __restrict__ eoff,
    const float* __restrict__ x, unsigned short* __restrict__ s,
    const float* __restrict__ Wr, const float* __restrict__ W0w,
    unsigned short* __restrict__ Wt2,
    int E, int N, int R, int nh, int nx)
{
    __shared__ float t[64][65];
    const int bid = blockIdx.x, tid = threadIdx.x;
    const int K = (R + 1) * 256;
    if (bid < nh) {
        int i = bid * 256 + tid;
        if (i < E) eoff[i] = atomicAdd(&deg[et[i] * N + dst[i]], 1);
    } else if (bid < nh + nx) {
        int id = (bid - nh) * 256 + tid;
        int n = id >> 6, c4 = id & 63;
        if (n < N) {
            float4 v = *reinterpret_cast<const float4*>(&x[((size_t)n << 8) + (c4 << 2)]);
            ushort4 h;
            h.x = f2bf(v.x); h.y = f2bf(v.y); h.z = f2bf(v.z); h.w = f2bf(v.w);
            *reinterpret_cast<ushort4*>(&s[(size_t)n * K + (K - 256) + (c4 << 2)]) = h;
        }
    } else {
        int tb = bid - nh - nx;              // (R+1)*16 tiles
        int sl = tb >> 4, d0 = ((tb >> 2) & 3) * 64, o0 = (tb & 3) * 64;
        if (sl < R) {
            #pragma unroll
            for (int j = 0; j < 16; ++j) {
                int idx = j * 256 + tid;
                int dr = idx >> 6, oc = idx & 63;
                t[dr][oc] = Wr[((size_t)sl * 256 + d0 + dr) * 256 + o0 + oc];
            }
            __syncthreads();
            #pragma unroll
            for (int j = 0; j < 4; ++j) {
                int idx = j * 256 + tid;
                int orow = idx >> 4, dc4 = (idx & 15) << 2;
                ushort4 h;
                h.x = f2bf(t[dc4 + 0][orow]); h.y = f2bf(t[dc4 + 1][orow]);
                h.z = f2bf(t[dc4 + 2][orow]); h.w = f2bf(t[dc4 + 3][orow]);
                *reinterpret_cast<ushort4*>(&Wt2[(size_t)(o0 + orow) * K + sl * 256 + d0 + dc4]) = h;
            }
        } else {
            #pragma unroll
            for (int j = 0; j < 4; ++j) {
                int idx = j * 256 + tid;
                int orow = idx >> 4, dc4 = (idx & 15) << 2;
                float4 v = *reinterpret_cast<const float4*>(&W0w[(size_t)(o0 + orow) * 256 + d0 + dc4]);
                ushort4 h;
                h.x = f2bf(v.x); h.y = f2bf(v.y); h.z = f2bf(v.z); h.w = f2bf(v.w);
                *reinterpret_cast<ushort4*>(&Wt2[(size_t)(o0 + orow) * K + sl * 256 + d0 + dc4]) = h;
            }
        }
    }
}

// ---- 2-level exclusive scan over B bins (chunk=256) ----
__global__ void scan1_kernel(const int* __restrict__ deg, int* __restrict__ local,
                             int* __restrict__ bsum, int B) {
    __shared__ int tmp[256];
    int t = threadIdx.x, g = blockIdx.x * 256 + t;
    int v = (g < B) ? deg[g] : 0;
    tmp[t] = v; __syncthreads();
    for (int o = 1; o < 256; o <<= 1) {
        int u = (t >= o) ? tmp[t - o] : 0;
        __syncthreads();
        tmp[t] += u;
        __syncthreads();
    }
    if (g < B) local[g] = tmp[t] - v;
    if (t == 255) bsum[blockIdx.x] = tmp[t];
}

__global__ void scan2_kernel(const int* __restrict__ bsum, int* __restrict__ base, int nc) {
    __shared__ int tmp[1024];
    int t = threadIdx.x;
    int v = (t < nc) ? bsum[t] : 0;
    tmp[t] = v; __syncthreads();
    for (int o = 1; o < 1024; o <<= 1) {
        int u = (t >= o) ? tmp[t - o] : 0;
        __syncthreads();
        tmp[t] += u;
        __syncthreads();
    }
    if (t < nc) base[t] = tmp[t] - v;
}

// ---- bucket edges (atomic-free): pos = local+base+eoff ----
__global__ void scatter_ids_kernel(const int* __restrict__ src, const int* __restrict__ dst,
                                   const int* __restrict__ et, const int* __restrict__ local,
                                   const int* __restrict__ base, const int* __restrict__ eoff,
                                   int* __restrict__ srcs, int E, int N) {
    int i = blockIdx.x * blockDim.x + threadIdx.x;
    if (i < E) {
        int b = et[i] * N + dst[i];
        srcs[local[b] + base[b >> 8] + eoff[i]] = src[i];
    }
}

// ---- segment reduce: half-wave (32 lanes x 16B) per (r,dn) bin; 2 bins/wave ----
__global__ __launch_bounds__(256) void reduce_kernel(
    const int* __restrict__ srcs, const int* __restrict__ deg,
    const int* __restrict__ local, const int* __restrict__ base,
    unsigned short* __restrict__ s, int N, int R)
{
    const int K = (R + 1) * 256;
    const int r = blockIdx.y;
    const int dn = blockIdx.x * 8 + (threadIdx.x >> 5);
    if (dn >= N) return;
    const int lane = threadIdx.x & 31;
    const int bin = r * N + dn;
    const int cnt = deg[bin];
    const int st  = local[bin] + base[bin >> 8];

    float a0 = 0.f, a1 = 0.f, a2 = 0.f, a3 = 0.f;
    float a4 = 0.f, a5 = 0.f, a6 = 0.f, a7 = 0.f;
    for (int c0 = 0; c0 < cnt; c0 += 32) {
        int sv = 0;
        if (c0 + lane < cnt) sv = srcs[st + c0 + lane];
        int m = cnt - c0; if (m > 32) m = 32;
        for (int i = 0; i < m; ++i) {
            int sn = __shfl(sv, i, 32);
            const uint4 v = *reinterpret_cast<const uint4*>(
                &s[(size_t)sn * K + (K - 256) + (lane << 3)]);
            a0 += blo(v.x); a1 += bhi(v.x);
            a2 += blo(v.y); a3 += bhi(v.y);
            a4 += blo(v.z); a5 += bhi(v.z);
            a6 += blo(v.w); a7 += bhi(v.w);
        }
    }
    if (cnt > 0) {
        float sc = 1.0f / (float)cnt;
        a0 *= sc; a1 *= sc; a2 *= sc; a3 *= sc;
        a4 *= sc; a5 *= sc; a6 *= sc; a7 *= sc;
    }
    uint4 o;
    o.x = pack2(a0, a1); o.y = pack2(a2, a3);
    o.z = pack2(a4, a5); o.w = pack2(a6, a7);
    *reinterpret_cast<uint4*>(&s[(size_t)dn * K + (r << 8) + (lane << 3)]) = o;
}

// ---- dense GEMM (R13 core, uneven split-K, bf16 LDS-repack epilogue) ----
// C_partial[z][M,256](bf16) = A[M,Kz](s) * B[256,Kz](Wt2)^T
// Grid (2, nM, KZ); XCD-chunked bijective swizzle; tile 128x128, 4 waves 2x2;
// BK=64; A dbuf (2 ahead), B single-buffered; global_load_lds + XOR swizzle +
// counted vmcnt(4); LDS 48KB -> 3 blocks/CU. Epilogue: acc -> LDS bf16 tile
// (repack, R14-verified) -> coalesced uint4 stores (no scalar-store penalty).
__global__ __launch_bounds__(256) void gemm_kernel(
    const unsigned short* __restrict__ S, const unsigned short* __restrict__ Wt2,
    unsigned short* __restrict__ pbuf, int M, int K, int ktot, int KZ)
{
    __shared__ __align__(16) unsigned short ldsA[2][8192];
    __shared__ __align__(16) unsigned short ldsB[8192];
    const int tid = threadIdx.x;
    const int lane = tid & 63, w = tid >> 6;
    const int wm = w & 1, wn = w >> 1;

    // XCD-chunked swizzle: linear id (x fastest), chunk-remap mod 8
    const int nM = gridDim.y;
    const int nwg = 2 * nM * gridDim.z;
    int L = blockIdx.x + 2 * (blockIdx.y + nM * blockIdx.z);
    if ((nwg & 7) == 0) { int q = nwg >> 3; L = (L & 7) * q + (L >> 3); }
    const int z = L / (2 * nM);
    const int rem = L - z * (2 * nM);
    const int m0 = (rem >> 1) * 128, n0 = (rem & 1) * 128;
    const int kb_ = ktot / KZ;
    const int krem = ktot - kb_ * KZ;
    const int ksteps = kb_ + (z < krem ? 1 : 0);
    const int kstart = (z * kb_ + (z < krem ? z : krem)) * 64;
    const size_t rowb = (size_t)K * 2;

    f32x4 acc[4][4] = {};

    const int flat_base = w * 4 * 64 + lane;

#define STAGE_A(buf, kstep)                                                               \
    {                                                                                     \
        const int kb = (kstart + (kstep) * 64) * 2;                                       \
        _Pragma("unroll")                                                                 \
        for (int i = 0; i < 4; ++i) {                                                     \
            int flat = flat_base + i * 64;                                                \
            int row = flat >> 3, seg = flat & 7;                                          \
            int gr = m0 + row; gr = gr < M ? gr : M - 1;                                  \
            const char* gp = (const char*)S + (size_t)gr * rowb + kb                      \
                             + ((seg * 16) ^ ((row & 7) << 4));                           \
            unsigned short* lp = &ldsA[buf][(w * 4 + i) * 512];                           \
            __builtin_amdgcn_global_load_lds(                                             \
                (const __attribute__((address_space(1))) void*)gp,                        \
                (__attribute__((address_space(3))) void*)lp, 16, 0, 0);                   \
        }                                                                                 \
    }

#define STAGE_B(kstep)                                                                    \
    {                                                                                     \
        const int kb = (kstart + (kstep) * 64) * 2;                                       \
        _Pragma("unroll")                                                                 \
        for (int i = 0; i < 4; ++i) {                                                     \
            int flat = flat_base + i * 64;                                                \
            int row = flat >> 3, seg = flat & 7;                                          \
            const char* gp = (const char*)Wt2 + (size_t)(n0 + row) * rowb + kb            \
                             + ((seg * 16) ^ ((row & 7) << 4));                           \
            unsigned short* lp = &ldsB[(w * 4 + i) * 512];                                \
            __builtin_amdgcn_global_load_lds(                                             \
                (const __attribute__((address_space(1))) void*)gp,                        \
                (__attribute__((address_space(3))) void*)lp, 16, 0, 0);                   \
        }                                                                                 \
    }

#define COMPUTE(buf)                                                                      \
    {                                                                                     \
        _Pragma("unroll")                                                                 \
        for (int kk = 0; kk < 2; ++kk) {                                                  \
            bf16x8 af[4], bfr[4];                                                         \
            _Pragma("unroll")                                                             \
            for (int m = 0; m < 4; ++m) {                                                 \
                int row = wm * 64 + m * 16 + (lane & 15);                                 \
                int colb = (kk * 64 + ((lane >> 4) << 4)) ^ ((row & 7) << 4);             \
                af[m] = *reinterpret_cast<const bf16x8*>(                                 \
                    (const char*)&ldsA[buf][0] + row * 128 + colb);                       \
            }                                                                             \
            _Pragma("unroll")                                                             \
            for (int n = 0; n < 4; ++n) {                                                 \
                int row = wn * 64 + n * 16 + (lane & 15);                                 \
                int colb = (kk * 64 + ((lane >> 4) << 4)) ^ ((row & 7) << 4);             \
                bfr[n] = *reinterpret_cast<const bf16x8*>(                                \
                    (const char*)&ldsB[0] + row * 128 + colb);                            \
            }                                                                             \
            __builtin_amdgcn_s_setprio(1);                                                \
            _Pragma("unroll")                                                             \
            for (int m = 0; m < 4; ++m)                                                   \
                _Pragma("unroll")                                                         \
                for (int n = 0; n < 4; ++n)                                               \
                    acc[m][n] = __builtin_amdgcn_mfma_f32_16x16x32_bf16(                  \
                        af[m], bfr[n], acc[m][n], 0, 0, 0);                               \
            __builtin_amdgcn_s_setprio(0);                                                \
        }                                                                                 \
    }

    STAGE_A(0, 0)
    STAGE_B(0)
    STAGE_A(1, 1)
    asm volatile("s_waitcnt vmcnt(4)" ::: "memory");
    __builtin_amdgcn_s_barrier();

    for (int t = 0; t < ksteps; ++t) {
        COMPUTE(t & 1)
        asm volatile("s_waitcnt lgkmcnt(0)" ::: "memory");
        __builtin_amdgcn_sched_barrier(0);
        __builtin_amdgcn_s_barrier();
        if (t + 1 < ksteps) {
            STAGE_B(t + 1)
            if (t + 2 < ksteps) {
                STAGE_A(t & 1, t + 2)
                asm volatile("s_waitcnt vmcnt(4)" ::: "memory");
            } else {
                asm volatile("s_waitcnt vmcnt(0)" ::: "memory");
            }
            __builtin_amdgcn_s_barrier();
        }
    }
#undef STAGE_A
#undef STAGE_B
#undef COMPUTE

    // ---- epilogue (R14-verified): repack acc -> LDS bf16 tile -> coalesced stores ----
    unsigned short* ldsC = &ldsA[0][0];   // 32 KB, free after final barrier
    const int lr = wm * 64 + ((lane >> 4) << 2);
    const int lc = wn * 64 + (lane & 15);
    #pragma unroll
    for (int n = 0; n < 4; ++n)
        #pragma unroll
        for (int m = 0; m < 4; ++m)
            #pragma unroll
            for (int j = 0; j < 4; ++j)
                ldsC[(lr + m * 16 + j) * 128 + lc + n * 16] = f2bf(acc[m][n][j]);
    __syncthreads();
    unsigned short* dstp = pbuf + (size_t)z * M * 256;
    #pragma unroll
    for (int i = 0; i < 8; ++i) {
        int idx = tid + i * 256;          // 0..2047
        int row = idx >> 4, ch = idx & 15;
        int gr = m0 + row;
        if (gr < M)
            *reinterpret_cast<uint4*>(&dstp[(size_t)gr * 256 + n0 + ch * 8]) =
                *reinterpret_cast<const uint4*>(&ldsC[row * 128 + ch * 8]);
    }
}

// ---- combine bf16 split-K partials + bias -> f32 out (R9-verified) ----
__global__ void combine_kernel(const unsigned short* __restrict__ pbuf,
                               const float* __restrict__ bias,
                               float* __restrict__ out, int M, int KZ) {
    int id = blockIdx.x * blockDim.x + threadIdx.x;
    if (id >= M * 64) return;
    int n = id >> 6, c4 = id & 63;
    const float4 bv = *reinterpret_cast<const float4*>(&bias[c4 << 2]);
    float4 a = bv;
    for (int kz = 0; kz < KZ; ++kz) {
        uint2 v = *reinterpret_cast<const uint2*>(
            &pbuf[(size_t)kz * M * 256 + ((size_t)n << 8) + (c4 << 2)]);
        a.x += blo(v.x); a.y += bhi(v.x);
        a.z += blo(v.y); a.w += bhi(v.y);
    }
    *reinterpret_cast<float4*>(&out[((size_t)n << 8) + (c4 << 2)]) = a;
}

extern "C" void kernel_launch(void* const* d_in, const int* in_sizes, int n_in,
                              void* d_out, int out_size, void* d_ws, size_t ws_size,
                              hipStream_t stream) {
    const float* x   = (const float*)d_in[0];
    const float* Wr  = (const float*)d_in[1];
    const float* W0w = (const float*)d_in[2];
    const float* W0b = (const float*)d_in[3];
    const int*   eidx= (const int*)d_in[4];
    const int*   et  = (const int*)d_in[5];
    const int N = in_sizes[0] / 256;      // nodes (10000)
    const int R = in_sizes[1] / 65536;    // relations (16)
    const int E = in_sizes[5];            // edges (320000)
    const int* src = eidx;
    const int* dst = eidx + E;
    float* out = (float*)d_out;

    const int B = R * N;                  // bins
    const int NC = (B + 255) / 256;       // scan chunks (<=1024)
    const int K = (R + 1) * 256;          // 4352

    // ---- workspace layout: [region0 = max(pbuf bf16, sortbufs)] [Wt2] [s] ----
    const size_t sz_pslice = (size_t)N * 256 * 2;                 // bf16 partial slice
    const size_t sz_sort = (((size_t)B * 4 + 255) & ~255UL) * 2   // deg, local
                         + (((size_t)E * 4 + 255) & ~255UL) * 2   // eoff, srcs
                         + 2 * 4096;                              // bsum, base
    const size_t sz_wt2 = (size_t)256 * K * 2;
    const size_t sz_s   = (size_t)N * K * 2;
    int KZ = 1;
    for (int kz = 8; kz >= 1; kz >>= 1) {
        size_t r0 = (kz > 1) ? (size_t)kz * sz_pslice : sz_pslice;
        if (sz_sort > r0) r0 = sz_sort;
        size_t need = ((r0 + 255) & ~255UL) + ((sz_wt2 + 255) & ~255UL) + sz_s + 1024;
        if (need <= ws_size || kz == 1) { KZ = kz; break; }
    }

    char* ws = (char*)d_ws;
    size_t off = 0;
    auto alloc = [&](size_t bytes) { void* p = ws + off; off = (off + bytes + 255) & ~(size_t)255; return p; };
    unsigned short* pbuf = (unsigned short*)ws;  // aliases sort bufs (dead before gemm)
    int* deg    = (int*)alloc((size_t)B * 4);
    int* local  = (int*)alloc((size_t)B * 4);
    int* bsum   = (int*)alloc(4096);
    int* base   = (int*)alloc(4096);
    int* eoff   = (int*)alloc((size_t)E * 4);
    int* srcs   = (int*)alloc((size_t)E * 4);
    size_t region0 = (size_t)KZ * sz_pslice;
    if (off > region0) region0 = off;
    off = (region0 + 255) & ~(size_t)255;
    unsigned short* Wt2 = (unsigned short*)alloc(sz_wt2);
    unsigned short* s   = (unsigned short*)alloc(sz_s);

    zero_kernel<<<(B / 4 + 255) / 256, 256, 0, stream>>>(deg, B);
    {
        const int nh = (E + 255) / 256;
        const int nx = (N * 64 + 255) / 256;
        const int nwT = (R + 1) * 16;
        prep_kernel<<<nh + nx + nwT, 256, 0, stream>>>(dst, et, deg, eoff, x, s,
                                                       Wr, W0w, Wt2, E, N, R, nh, nx);
    }
    scan1_kernel<<<NC, 256, 0, stream>>>(deg, local, bsum, B);
    scan2_kernel<<<1, 1024, 0, stream>>>(bsum, base, NC);
    scatter_ids_kernel<<<(E + 255) / 256, 256, 0, stream>>>(src, dst, et, local, base, eoff, srcs, E, N);
    {
        dim3 g((N + 7) / 8, R);
        reduce_kernel<<<g, 256, 0, stream>>>(srcs, deg, local, base, s, N, R);
    }
    {
        const int ktot = K / 64;                  // 68
        const int nM = (N + 127) / 128;           // 79
        dim3 grid(2, nM, KZ);                     // bx=n-tile, by=m-tile, bz=kz
        gemm_kernel<<<grid, 256, 0, stream>>>(s, Wt2, pbuf, N, K, ktot, KZ);
        combine_kernel<<<(N * 64 + 255) / 256, 256, 0, stream>>>(pbuf, W0b, out, N, KZ);
    }
}